// Round 5
// baseline (163.125 us; speedup 1.0000x reference)
//
#include <hip/hip_runtime.h>
#include <math.h>

#define B_ 2
#define T_ 8
#define N_ 2048
#define F_ 64
#define TI 8                  // i-rows per block (A uses rows 0-7 of 16x16 MFMA)
#define JC 64
#define JCP 72
#define NCH (N_ / 2 / JC)     // 16 chunks per block (2-way j split)
#define LOG2E 1.44269504088896f

typedef __attribute__((ext_vector_type(8))) short short8;
typedef __attribute__((ext_vector_type(4))) float f32x4;

__device__ __forceinline__ unsigned short f2bf(float x) {
  unsigned u = __float_as_uint(x);
  u += 0x7FFFu + ((u >> 16) & 1u);
  return (unsigned short)(u >> 16);
}

__device__ __forceinline__ unsigned cvt_pk_bf16(float lo, float hi) {
  unsigned r;
  asm("v_cvt_pk_bf16_f32 %0, %1, %2" : "=v"(r) : "v"(lo), "v"(hi));
  return r;
}

// ---------------- prep: Wh = h@W (fp32), WhT bf16 [bt][f][j], Wh1/Wh2 (pre-scaled by log2e)
__global__ __launch_bounds__(256) void prep_kernel(
    const float* __restrict__ h, const float* __restrict__ W,
    const float* __restrict__ a, unsigned short* __restrict__ WhT,
    float* __restrict__ Wh1, float* __restrict__ Wh2) {
  __shared__ float Ws[64][64];
  __shared__ float hs[64][64];
  __shared__ float Whs[64][65];
  const int tid = threadIdx.x;
  const int row0 = blockIdx.x * 64;   // row in flattened [B*T*N]
  const int bt = row0 >> 11;
  const int j0 = row0 & 2047;
  for (int i = tid; i < 4096; i += 256) Ws[i >> 6][i & 63] = W[i];
  for (int i = tid; i < 4096; i += 256) hs[i >> 6][i & 63] = h[(size_t)row0 * 64 + i];
  __syncthreads();
  const int f = tid & 63;
  const int rq = tid >> 6;
  float acc[16];
#pragma unroll
  for (int m = 0; m < 16; ++m) acc[m] = 0.f;
#pragma unroll 4
  for (int k = 0; k < 64; ++k) {
    const float wvv = Ws[k][f];
#pragma unroll
    for (int m = 0; m < 16; ++m) acc[m] = fmaf(hs[rq * 16 + m][k], wvv, acc[m]);
  }
#pragma unroll
  for (int m = 0; m < 16; ++m) Whs[rq * 16 + m][f] = acc[m];
  __syncthreads();
  {
    const int r = tid >> 2, q = tid & 3;
    float s1 = 0.f, s2 = 0.f;
#pragma unroll
    for (int k = 0; k < 16; ++k) {
      const float v = Whs[r][q * 16 + k];
      s1 = fmaf(v, a[q * 16 + k], s1);
      s2 = fmaf(v, a[64 + q * 16 + k], s2);
    }
    s1 += __shfl_xor(s1, 1); s1 += __shfl_xor(s1, 2);
    s2 += __shfl_xor(s2, 1); s2 += __shfl_xor(s2, 2);
    if (q == 0) {
      // pre-scale by log2(e): LeakyReLU is positively homogeneous, so
      // exp(LRelu(w1+w2)) == exp2(LRelu(log2e*w1 + log2e*w2))
      Wh1[(size_t)bt * N_ + j0 + r] = s1 * LOG2E;
      Wh2[(size_t)bt * N_ + j0 + r] = s2 * LOG2E;
    }
  }
  {
    const int ff = tid & 63, cp = tid >> 6;
#pragma unroll
    for (int cc = 0; cc < 2; ++cc) {
      const int c = cp * 2 + cc;
      short8 v;
#pragma unroll
      for (int k = 0; k < 8; ++k) v[k] = (short)f2bf(Whs[c * 8 + k][ff]);
      *(short8*)(WhT + ((size_t)bt * 64 + ff) * N_ + j0 + c * 8) = v;
    }
  }
}

// ---------------- main: softmax-over-T attention + MFMA PV -> fp32 partials
// grid 1024: jh = bx&1, itile = (bx>>1)&255 (8 rows each), b = bx>>9
// jh0 partial -> out (fp32), jh1 partial -> part (fp32). Disjoint words.
__global__ __launch_bounds__(512, 8) void gat_mfma(
    const unsigned short* __restrict__ WhT, const float* __restrict__ Wh1,
    const float* __restrict__ Wh2, const int* __restrict__ adj,
    float* __restrict__ out, float* __restrict__ part) {
  __shared__ unsigned short atts[2][T_][16][JCP];  // 36864 B (rows 8-15 never written)
  __shared__ float wh2s[2][T_][JC];                // 4096 B -> total 40960 = 4 blocks/CU
  const int tid = threadIdx.x;
  const int jh = blockIdx.x & 1;
  const int i0 = ((blockIdx.x >> 1) & 255) * TI;
  const int b = blockIdx.x >> 9;
  const int jbase = jh * (N_ / 2);

  const int wv = tid >> 6;        // wave id == t; also softmax i-row (sii == wv)
  const int lane = tid & 63;
  const int col = lane & 15;
  const int kg = lane >> 4;

  const unsigned short* wtb = WhT + (size_t)(b * T_ + wv) * F_ * N_;
  const float* wh2b = Wh2 + (size_t)b * T_ * N_;
  const int* adjrow = adj + (size_t)(i0 + wv) * N_ + jbase;  // softmax row = wv

  // Wh1 for this thread's softmax i-row (wave-uniform broadcast loads, once)
  float w1r[T_];
#pragma unroll
  for (int t = 0; t < T_; ++t) w1r[t] = Wh1[(size_t)(b * T_ + t) * N_ + i0 + wv];

  f32x4 acc[4];
#pragma unroll
  for (int nt = 0; nt < 4; ++nt) acc[nt] = {0.f, 0.f, 0.f, 0.f};

  // prologue: stage wh2 chunk 0, prefetch adj chunk 0
  wh2s[0][wv][lane] = wh2b[(size_t)wv * N_ + jbase + lane];
  int ad = adjrow[lane];
  __syncthreads();

  for (int c = 0; c < NCH; ++c) {
    const int j0 = jbase + c * JC;
    const int buf = c & 1;
    // --- issue B-fragment global loads early
    short8 breg[4][2];
#pragma unroll
    for (int nt = 0; nt < 4; ++nt)
#pragma unroll
      for (int ks = 0; ks < 2; ++ks)
        breg[nt][ks] = *(const short8*)(wtb + (size_t)(nt * 16 + col) * N_ +
                                        j0 + ks * 32 + kg * 8);
    // --- stage next chunk's Wh2 (safe: buf^1 readers all passed barrier(c-1))
    if (c + 1 < NCH)
      wh2s[buf ^ 1][wv][lane] = wh2b[(size_t)wv * N_ + j0 + JC + lane];
    // --- prefetch next chunk's adj
    int adn = ad;
    if (c + 1 < NCH) adn = adjrow[(c + 1) * JC + lane];

    // --- softmax over T, one (i=wv, j=lane) pair per thread; no max pass needed
    {
      float e[T_];
      float s = 0.f;
#pragma unroll
      for (int t = 0; t < T_; ++t) {
        float x = w1r[t] + wh2s[buf][t][lane];
        x = fmaxf(x, 0.2f * x);   // LeakyReLU (alpha<1, scale-commuting)
        e[t] = __builtin_amdgcn_exp2f(x);
        s += e[t];
      }
      // adj==0 -> all-NEG_INF column -> softmax over t uniform 1/8
      const float rr = ad > 0 ? __builtin_amdgcn_rcpf(s) : 0.f;
      const float dd = ad > 0 ? 0.f : 0.125f;
#pragma unroll
      for (int t = 0; t < T_; ++t) {
        const float av = fmaf(e[t], rr, dd);
        atts[buf][t][wv][lane] = (unsigned short)cvt_pk_bf16(av, av);
      }
    }
    ad = adn;
    __syncthreads();
    // --- MFMA: A = att[8i x 64j] in rows 0-7 (rows 8-15 stale: affects only
    //     C rows 8-15, never stored), B = WhT[64f x 64j], both bf16
    const unsigned short* ab = &atts[buf][wv][col][kg * 8];
    const short8 a0 = *(const short8*)ab;
    const short8 a1 = *(const short8*)(ab + 32);
#pragma unroll
    for (int nt = 0; nt < 4; ++nt) {
      acc[nt] = __builtin_amdgcn_mfma_f32_16x16x32_bf16(a0, breg[nt][0], acc[nt], 0, 0, 0);
      acc[nt] = __builtin_amdgcn_mfma_f32_16x16x32_bf16(a1, breg[nt][1], acc[nt], 0, 0, 0);
    }
  }

  // ---- epilogue: fp32 partial store. C/D: col=lane&15, row=(lane>>4)*4+reg.
  // Only rows 0-7 (kg<2) are valid/stored.
  if (kg < 2) {
    float* dst = jh ? part : out;
    float* ob = dst + ((size_t)(b * T_ + wv) * N_ + i0) * F_;
#pragma unroll
    for (int nt = 0; nt < 4; ++nt) {
#pragma unroll
      for (int r = 0; r < 4; ++r) {
        const int row = kg * 4 + r;
        ob[(size_t)row * F_ + nt * 16 + col] = acc[nt][r];
      }
    }
  }
}

// ---------------- combine partials + ELU
__global__ __launch_bounds__(256) void combine_elu(
    float* __restrict__ out, const float* __restrict__ part) {
  const size_t i = ((size_t)blockIdx.x * 256 + threadIdx.x) * 4;
  f32x4 o = *(const f32x4*)(out + i);
  const f32x4 p = *(const f32x4*)(part + i);
#pragma unroll
  for (int k = 0; k < 4; ++k) {
    const float x = o[k] + p[k];
    o[k] = x > 0.f ? x : expm1f(x);
  }
  *(f32x4*)(out + i) = o;
}

extern "C" void kernel_launch(void* const* d_in, const int* in_sizes, int n_in,
                              void* d_out, int out_size, void* d_ws, size_t ws_size,
                              hipStream_t stream) {
  const float* h   = (const float*)d_in[0];
  const float* W   = (const float*)d_in[1];
  const float* a   = (const float*)d_in[2];
  const int*   adj = (const int*)d_in[3];
  float* out = (float*)d_out;

  const size_t whtBytes = (size_t)B_ * T_ * F_ * N_ * 2;    // 4MB
  unsigned short* WhT = (unsigned short*)d_ws;
  float* Wh1  = (float*)((char*)d_ws + whtBytes);
  float* Wh2  = Wh1 + (size_t)B_ * T_ * N_;
  float* part = Wh2 + (size_t)B_ * T_ * N_;                 // 8MB fp32

  hipLaunchKernelGGL(prep_kernel, dim3(B_ * T_ * N_ / 64), dim3(256), 0, stream,
                     h, W, a, WhT, Wh1, Wh2);
  hipLaunchKernelGGL(gat_mfma, dim3(B_ * 256 * 2), dim3(512), 0, stream,
                     WhT, Wh1, Wh2, adj, out, part);
  hipLaunchKernelGGL(combine_elu, dim3(B_ * T_ * N_ * F_ / (256 * 4)), dim3(256),
                     0, stream, out, part);
}

// Round 6
// 62.642 us; speedup vs baseline: 2.6041x; 2.6041x over previous
//
#include <hip/hip_runtime.h>
#include <math.h>

#define B_ 2
#define T_ 8
#define N_ 2048
#define F_ 64
#define TI 32                 // i-rows per block: two 16-row A-tiles share B-frags
#define JC 64
#define JCP 72
#define LOG2E 1.44269504088896f
#define PART_STRIDE ((size_t)B_ * T_ * N_ * F_)   // floats per partial buffer

typedef __attribute__((ext_vector_type(8))) short short8;
typedef __attribute__((ext_vector_type(4))) float f32x4;

__device__ __forceinline__ unsigned short f2bf(float x) {
  unsigned u = __float_as_uint(x);
  u += 0x7FFFu + ((u >> 16) & 1u);
  return (unsigned short)(u >> 16);
}

__device__ __forceinline__ unsigned cvt_pk_bf16(float lo, float hi) {
  unsigned r;
  asm("v_cvt_pk_bf16_f32 %0, %1, %2" : "=v"(r) : "v"(lo), "v"(hi));
  return r;
}

// ---------------- prep: Wh = h@W (fp32), WhT bf16 [bt][f][j], Wh1/Wh2 (pre-scaled by log2e)
__global__ __launch_bounds__(256) void prep_kernel(
    const float* __restrict__ h, const float* __restrict__ W,
    const float* __restrict__ a, unsigned short* __restrict__ WhT,
    float* __restrict__ Wh1, float* __restrict__ Wh2) {
  __shared__ float Ws[64][64];
  __shared__ float hs[64][64];
  __shared__ float Whs[64][65];
  const int tid = threadIdx.x;
  const int row0 = blockIdx.x * 64;   // row in flattened [B*T*N]
  const int bt = row0 >> 11;
  const int j0 = row0 & 2047;
  for (int i = tid; i < 4096; i += 256) Ws[i >> 6][i & 63] = W[i];
  for (int i = tid; i < 4096; i += 256) hs[i >> 6][i & 63] = h[(size_t)row0 * 64 + i];
  __syncthreads();
  const int f = tid & 63;
  const int rq = tid >> 6;
  float acc[16];
#pragma unroll
  for (int m = 0; m < 16; ++m) acc[m] = 0.f;
#pragma unroll 4
  for (int k = 0; k < 64; ++k) {
    const float wvv = Ws[k][f];
#pragma unroll
    for (int m = 0; m < 16; ++m) acc[m] = fmaf(hs[rq * 16 + m][k], wvv, acc[m]);
  }
#pragma unroll
  for (int m = 0; m < 16; ++m) Whs[rq * 16 + m][f] = acc[m];
  __syncthreads();
  {
    const int r = tid >> 2, q = tid & 3;
    float s1 = 0.f, s2 = 0.f;
#pragma unroll
    for (int k = 0; k < 16; ++k) {
      const float v = Whs[r][q * 16 + k];
      s1 = fmaf(v, a[q * 16 + k], s1);
      s2 = fmaf(v, a[64 + q * 16 + k], s2);
    }
    s1 += __shfl_xor(s1, 1); s1 += __shfl_xor(s1, 2);
    s2 += __shfl_xor(s2, 1); s2 += __shfl_xor(s2, 2);
    if (q == 0) {
      // pre-scale by log2(e): LeakyReLU is positively homogeneous, so
      // exp(LRelu(w1+w2)) == exp2(LRelu(log2e*w1 + log2e*w2))
      Wh1[(size_t)bt * N_ + j0 + r] = s1 * LOG2E;
      Wh2[(size_t)bt * N_ + j0 + r] = s2 * LOG2E;
    }
  }
  {
    const int ff = tid & 63, cp = tid >> 6;
#pragma unroll
    for (int cc = 0; cc < 2; ++cc) {
      const int c = cp * 2 + cc;
      short8 v;
#pragma unroll
      for (int k = 0; k < 8; ++k) v[k] = (short)f2bf(Whs[c * 8 + k][ff]);
      *(short8*)(WhT + ((size_t)bt * 64 + ff) * N_ + j0 + c * 8) = v;
    }
  }
}

// ---------------- main: softmax-over-T attention + MFMA PV -> fp32 partials
// TI=32: two 16-row A-tiles per wave reuse one set of B-fragments (halves L2 traffic).
// njq-way j split; jq=0 -> out, jq>=1 -> parts[(jq-1)]. Disjoint fp32 buffers.
__global__ __launch_bounds__(512, 4) void gat_mfma(
    const unsigned short* __restrict__ WhT, const float* __restrict__ Wh1,
    const float* __restrict__ Wh2, const int* __restrict__ adj,
    float* __restrict__ out, float* __restrict__ parts, const int njq) {
  __shared__ unsigned short atts[2][T_][TI][JCP];  // 73728 B
  __shared__ float wh2s[2][T_][JC];                // 4096 B -> 77824 total, 2 blocks/CU
  const int tid = threadIdx.x;
  const int jq = blockIdx.x % njq;
  const int rest = blockIdx.x / njq;
  const int i0 = (rest & 63) * TI;
  const int b = rest >> 6;
  const int jspan = N_ / njq;
  const int jbase = jq * jspan;
  const int nchunk = jspan / JC;

  const int wv = tid >> 6;        // wave id == t
  const int lane = tid & 63;
  const int col = lane & 15;
  const int kg = lane >> 4;

  const int sii = tid >> 4;          // softmax i-row 0..31
  const int sjj = (tid & 15) * 4;    // softmax j-cols sjj..sjj+3
  const int st = tid >> 6, sj = tid & 63;  // wh2 staging assignment

  const unsigned short* wtb = WhT + (size_t)(b * T_ + wv) * F_ * N_;
  const float* wh2b = Wh2 + (size_t)b * T_ * N_;
  const int* adjrow = adj + (size_t)(i0 + sii) * N_ + jbase;

  // Wh1 for this thread's softmax i-row (L2 broadcast loads, once per kernel)
  float w1r[T_];
#pragma unroll
  for (int t = 0; t < T_; ++t) w1r[t] = Wh1[(size_t)(b * T_ + t) * N_ + i0 + sii];

  f32x4 acc[2][4];
#pragma unroll
  for (int it = 0; it < 2; ++it)
#pragma unroll
    for (int nt = 0; nt < 4; ++nt) acc[it][nt] = {0.f, 0.f, 0.f, 0.f};

  // prologue: stage wh2 chunk 0, prefetch adj chunk 0
  wh2s[0][st][sj] = wh2b[(size_t)st * N_ + jbase + sj];
  int4 ad = *(const int4*)(adjrow + sjj);
  __syncthreads();

  for (int c = 0; c < nchunk; ++c) {
    const int j0 = jbase + c * JC;
    const int buf = c & 1;
    // --- issue B-fragment global loads early (shared by both A-tiles)
    short8 breg[4][2];
#pragma unroll
    for (int nt = 0; nt < 4; ++nt)
#pragma unroll
      for (int ks = 0; ks < 2; ++ks)
        breg[nt][ks] = *(const short8*)(wtb + (size_t)(nt * 16 + col) * N_ +
                                        j0 + ks * 32 + kg * 8);
    // --- stage next chunk's Wh2 (safe: buf^1 readers all passed barrier(c-1))
    if (c + 1 < nchunk)
      wh2s[buf ^ 1][st][sj] = wh2b[(size_t)st * N_ + j0 + JC + sj];
    // --- prefetch next chunk's adj
    int4 adn = ad;
    if (c + 1 < nchunk) adn = *(const int4*)(adjrow + (c + 1) * JC + sjj);

    // --- softmax over T: row sii, cols sjj..sjj+3 (2 register-light passes)
#pragma unroll
    for (int g = 0; g < 2; ++g) {
      const int c0 = sjj + 2 * g;
      const int a0i = g == 0 ? ad.x : ad.z;
      const int a1i = g == 0 ? ad.y : ad.w;
      float e0[T_], e1[T_];
      float s0 = 0.f, s1 = 0.f;
#pragma unroll
      for (int t = 0; t < T_; ++t) {
        const float2 w2 = *(const float2*)(&wh2s[buf][t][c0]);
        float x0 = w1r[t] + w2.x;
        float x1 = w1r[t] + w2.y;
        x0 = fmaxf(x0, 0.2f * x0);   // LeakyReLU (alpha<1, scale-commuting)
        x1 = fmaxf(x1, 0.2f * x1);
        e0[t] = __builtin_amdgcn_exp2f(x0);
        e1[t] = __builtin_amdgcn_exp2f(x1);
        s0 += e0[t];
        s1 += e1[t];
      }
      // adj==0 -> all-NEG_INF column -> softmax over t uniform 1/8
      const float r0 = a0i > 0 ? __builtin_amdgcn_rcpf(s0) : 0.f;
      const float r1 = a1i > 0 ? __builtin_amdgcn_rcpf(s1) : 0.f;
      const float d0 = a0i > 0 ? 0.f : 0.125f;
      const float d1 = a1i > 0 ? 0.f : 0.125f;
#pragma unroll
      for (int t = 0; t < T_; ++t) {
        const float av0 = fmaf(e0[t], r0, d0);
        const float av1 = fmaf(e1[t], r1, d1);
        *(unsigned*)&atts[buf][t][sii][c0] = cvt_pk_bf16(av0, av1);
      }
    }
    ad = adn;
    __syncthreads();
    // --- MFMA: two A-tiles (rows 0-15, 16-31) x 4 f-tiles, reusing breg
#pragma unroll
    for (int it = 0; it < 2; ++it) {
      const unsigned short* ab = &atts[buf][wv][it * 16 + col][kg * 8];
      const short8 a0 = *(const short8*)ab;
      const short8 a1 = *(const short8*)(ab + 32);
#pragma unroll
      for (int nt = 0; nt < 4; ++nt) {
        acc[it][nt] = __builtin_amdgcn_mfma_f32_16x16x32_bf16(a0, breg[nt][0], acc[it][nt], 0, 0, 0);
        acc[it][nt] = __builtin_amdgcn_mfma_f32_16x16x32_bf16(a1, breg[nt][1], acc[it][nt], 0, 0, 0);
      }
    }
  }

  // ---- epilogue: fp32 partial store. C/D: col=lane&15, row=(lane>>4)*4+reg
  float* dst = (jq == 0) ? out : (parts + (size_t)(jq - 1) * PART_STRIDE);
  float* ob = dst + ((size_t)(b * T_ + wv) * N_ + i0) * F_;
#pragma unroll
  for (int it = 0; it < 2; ++it) {
#pragma unroll
    for (int nt = 0; nt < 4; ++nt) {
#pragma unroll
      for (int r = 0; r < 4; ++r) {
        const int row = it * 16 + kg * 4 + r;
        ob[(size_t)row * F_ + nt * 16 + col] = acc[it][nt][r];
      }
    }
  }
}

// ---------------- combine partials + ELU
__global__ __launch_bounds__(256) void combine_elu(
    float* __restrict__ out, const float* __restrict__ parts, const int nparts) {
  const size_t i = ((size_t)blockIdx.x * 256 + threadIdx.x) * 4;
  f32x4 o = *(const f32x4*)(out + i);
  for (int p = 0; p < nparts; ++p) {
    const f32x4 q = *(const f32x4*)(parts + p * PART_STRIDE + i);
#pragma unroll
    for (int k = 0; k < 4; ++k) o[k] += q[k];
  }
#pragma unroll
  for (int k = 0; k < 4; ++k) o[k] = o[k] > 0.f ? o[k] : expm1f(o[k]);
  *(f32x4*)(out + i) = o;
}

extern "C" void kernel_launch(void* const* d_in, const int* in_sizes, int n_in,
                              void* d_out, int out_size, void* d_ws, size_t ws_size,
                              hipStream_t stream) {
  const float* h   = (const float*)d_in[0];
  const float* W   = (const float*)d_in[1];
  const float* a   = (const float*)d_in[2];
  const int*   adj = (const int*)d_in[3];
  float* out = (float*)d_out;

  const size_t whtBytes = (size_t)B_ * T_ * F_ * N_ * 2;    // 4MB
  const size_t vBytes   = (size_t)B_ * T_ * N_ * 4;         // 128KB
  const size_t partB    = PART_STRIDE * 4;                  // 8MB each

  unsigned short* WhT = (unsigned short*)d_ws;
  float* Wh1   = (float*)((char*)d_ws + whtBytes);
  float* Wh2   = Wh1 + (size_t)B_ * T_ * N_;
  float* parts = Wh2 + (size_t)B_ * T_ * N_;

  // 4-way j split needs 3 partial buffers; fall back to 2-way (1 buffer) if ws short
  const int njq = (ws_size >= whtBytes + 2 * vBytes + 3 * partB) ? 4
                : (ws_size >= whtBytes + 2 * vBytes + 1 * partB) ? 2 : 1;

  hipLaunchKernelGGL(prep_kernel, dim3(B_ * T_ * N_ / 64), dim3(256), 0, stream,
                     h, W, a, WhT, Wh1, Wh2);
  hipLaunchKernelGGL(gat_mfma, dim3(B_ * 64 * njq), dim3(512), 0, stream,
                     WhT, Wh1, Wh2, adj, out, parts, njq);
  if (njq > 1) {
    hipLaunchKernelGGL(combine_elu, dim3((unsigned)(PART_STRIDE / (256 * 4))), dim3(256),
                       0, stream, out, parts, njq - 1);
  } else {
    // njq==1: no partials; still need ELU over out
    hipLaunchKernelGGL(combine_elu, dim3((unsigned)(PART_STRIDE / (256 * 4))), dim3(256),
                       0, stream, out, parts, 0);
  }
}